// Round 1
// baseline (2736.438 us; speedup 1.0000x reference)
//
#include <hip/hip_runtime.h>
#include <math.h>

// Vanilla RNN: h_t = tanh(h_{t-1} @ wh + x_t @ wx + b), output h_T as [B,1,H].
// B=256, T=2048, H=256, all fp32.
//
// Design (round 0, correctness-first, all fp32):
//  - 256 blocks (one per batch row) x 512 threads (8 waves) -> 1 block/CU.
//    Recurrence is independent across batch rows => no grid sync ever.
//  - wh (256KB fp32) lives in REGISTERS, distributed: wave w owns k-slice
//    [w*32, w*32+32), lane owns columns j = lane*4..lane*4+4  => 128 VGPR.
//  - Per step: each lane does 128 FMAs (h broadcast from LDS x wh regs),
//    partials reduced across 8 waves via LDS, +xw, tanh, write h back to LDS.
//  - Input projection x@wx+b fused in, chunked 32 timesteps at a time:
//    stage x-chunk (32x256) and wx k-tiles (32x256) in LDS, accumulate in
//    registers, write xw chunk to LDS, then scan those 32 steps.
//  - No workspace used. No hipMalloc/Memcpy. Deterministic.

#define Bv 256
#define Tv 2048
#define Hv 256
#define TC 32           // timesteps per chunk
#define NCHUNK (Tv/TC)  // 64

__global__ __launch_bounds__(512, 2)
void HiddenLayer_704374636647_kernel(const float* __restrict__ x,
                                     const float* __restrict__ wx,
                                     const float* __restrict__ wh,
                                     const float* __restrict__ bias,
                                     float* __restrict__ out)
{
    __shared__ __align__(16) float xs[TC][Hv];       // x chunk           32KB
    __shared__ __align__(16) float xwc[TC][Hv];      // xw = x@wx+b chunk 32KB
    __shared__ __align__(16) float wxs[32][Hv];      // wx k-tile         32KB
    __shared__ __align__(16) float partial[8][Hv];   // per-wave partials  8KB
    __shared__ __align__(16) float h_lds[Hv];        // hidden state       1KB

    const int b    = blockIdx.x;      // batch row
    const int tid  = threadIdx.x;     // 0..511
    const int wave = tid >> 6;        // 0..7
    const int lane = tid & 63;        // 0..63
    const int j0   = lane * 4;        // 4 contiguous output columns per lane

    // ---- load this thread's wh slice into registers (k = wave*32+kk, j = j0+jj)
    float whr[32][4];
    {
        const float* p = wh + (size_t)(wave * 32) * Hv + j0;
        #pragma unroll
        for (int kk = 0; kk < 32; ++kk) {
            float4 v = *reinterpret_cast<const float4*>(p + (size_t)kk * Hv);
            whr[kk][0] = v.x; whr[kk][1] = v.y; whr[kk][2] = v.z; whr[kk][3] = v.w;
        }
    }
    float4 biasv = *reinterpret_cast<const float4*>(bias + j0);

    if (tid < Hv) h_lds[tid] = 0.0f;   // h_0 = 0 (barrier before first use below)

    const float* xb = x + (size_t)b * Tv * Hv;

    for (int c = 0; c < NCHUNK; ++c) {
        // ---- stage x chunk: xs[tt][k], 32x256 floats, 4 float4 per thread (coalesced)
        #pragma unroll
        for (int s = 0; s < 4; ++s) {
            int f  = tid + s * 512;        // float4 index 0..2047
            int tt = f >> 6;
            int k4 = (f & 63) * 4;
            *reinterpret_cast<float4*>(&xs[tt][k4]) =
                *reinterpret_cast<const float4*>(xb + (size_t)(c * TC + tt) * Hv + k4);
        }

        // ---- chunk GEMM: xwc[tt][j] = sum_k xs[tt][k] * wx[k][j] + bias[j]
        //      wave owns rows tt0..tt0+4, lane owns cols j0..j0+4 -> acc[4][4]
        float acc[4][4];
        #pragma unroll
        for (int i = 0; i < 4; ++i) {
            acc[i][0] = 0.f; acc[i][1] = 0.f; acc[i][2] = 0.f; acc[i][3] = 0.f;
        }
        const int tt0 = wave * 4;

        for (int k0 = 0; k0 < Hv; k0 += 32) {
            __syncthreads();   // prev wxs use done; also orders xs staging (first iter)
            #pragma unroll
            for (int s = 0; s < 4; ++s) {
                int f  = tid + s * 512;
                int kk = f >> 6;
                int k4 = (f & 63) * 4;
                *reinterpret_cast<float4*>(&wxs[kk][k4]) =
                    *reinterpret_cast<const float4*>(wx + (size_t)(k0 + kk) * Hv + k4);
            }
            __syncthreads();

            #pragma unroll
            for (int kq = 0; kq < 8; ++kq) {
                float xk[4][4];
                #pragma unroll
                for (int i = 0; i < 4; ++i) {
                    float4 v = *reinterpret_cast<const float4*>(&xs[tt0 + i][k0 + kq * 4]);
                    xk[i][0] = v.x; xk[i][1] = v.y; xk[i][2] = v.z; xk[i][3] = v.w;
                }
                #pragma unroll
                for (int e = 0; e < 4; ++e) {
                    float4 wv = *reinterpret_cast<const float4*>(&wxs[kq * 4 + e][j0]);
                    #pragma unroll
                    for (int i = 0; i < 4; ++i) {
                        acc[i][0] += xk[i][e] * wv.x;
                        acc[i][1] += xk[i][e] * wv.y;
                        acc[i][2] += xk[i][e] * wv.z;
                        acc[i][3] += xk[i][e] * wv.w;
                    }
                }
            }
        }

        __syncthreads();   // all waves done with wxs/xs compute
        #pragma unroll
        for (int i = 0; i < 4; ++i) {
            float4 v;
            v.x = acc[i][0] + biasv.x;
            v.y = acc[i][1] + biasv.y;
            v.z = acc[i][2] + biasv.z;
            v.w = acc[i][3] + biasv.w;
            *reinterpret_cast<float4*>(&xwc[tt0 + i][j0]) = v;
        }
        __syncthreads();   // xwc visible to all

        // ---- scan TC sequential steps
        for (int ts = 0; ts < TC; ++ts) {
            // broadcast-read this wave's h slice (uniform addr per wave -> broadcast)
            float hk[32];
            #pragma unroll
            for (int q = 0; q < 8; ++q) {
                float4 v = *reinterpret_cast<const float4*>(&h_lds[wave * 32 + q * 4]);
                hk[q*4+0] = v.x; hk[q*4+1] = v.y; hk[q*4+2] = v.z; hk[q*4+3] = v.w;
            }
            float a0 = 0.f, a1 = 0.f, a2 = 0.f, a3 = 0.f;
            #pragma unroll
            for (int kk = 0; kk < 32; ++kk) {
                a0 += hk[kk] * whr[kk][0];
                a1 += hk[kk] * whr[kk][1];
                a2 += hk[kk] * whr[kk][2];
                a3 += hk[kk] * whr[kk][3];
            }
            float4 pv; pv.x = a0; pv.y = a1; pv.z = a2; pv.w = a3;
            *reinterpret_cast<float4*>(&partial[wave][j0]) = pv;
            __syncthreads();

            if (tid < Hv) {
                float s = xwc[ts][tid];
                #pragma unroll
                for (int w = 0; w < 8; ++w) s += partial[w][tid];
                h_lds[tid] = tanhf(s);
            }
            __syncthreads();
        }
    }

    if (tid < Hv) out[(size_t)b * Hv + tid] = h_lds[tid];
}

extern "C" void kernel_launch(void* const* d_in, const int* in_sizes, int n_in,
                              void* d_out, int out_size, void* d_ws, size_t ws_size,
                              hipStream_t stream) {
    const float* x    = (const float*)d_in[0];   // [B,T,H]
    const float* wx   = (const float*)d_in[1];   // [H,H]
    const float* wh   = (const float*)d_in[2];   // [H,H]
    const float* bias = (const float*)d_in[3];   // [1,H]
    float* out = (float*)d_out;                  // [B,1,H]

    hipLaunchKernelGGL(HiddenLayer_704374636647_kernel,
                       dim3(Bv), dim3(512), 0, stream,
                       x, wx, wh, bias, out);
}

// Round 2
// 1175.277 us; speedup vs baseline: 2.3283x; 2.3283x over previous
//
#include <hip/hip_runtime.h>
#include <math.h>

// Vanilla RNN: h_t = tanh(h_{t-1} @ wh + x_t @ wx + b), out = h_T  [B,1,H]
// B=256, T=2048, H=256, fp32 in/out.
//
// Round 1 design:
//  - 256 blocks (1 batch row/CU) x 512 threads (8 waves). No grid sync.
//  - Projection xw = x@wx+b : f16 MFMA 16x16x32, f32 accum. wx B-frags live
//    in registers (64 VGPR/lane), A staged per 32-step chunk in LDS (padded).
//  - Recurrence: j-split. Wave w owns cols [w*32,w*32+32); lane l: col =
//    w*32+(l&31), k-half = l>>5 (128 k). wh in regs as 64 x f16x2 (64 VGPR).
//    Per step: 16 broadcast ds_read_b128 of h-half, 64 v_dot2_f32_f16 (f32
//    acc), shfl_xor(32) combine, fast tanh, f16 write of h. NO cross-wave
//    LDS reduce.
//  - h double-buffered -> ONE barrier/step, done as raw s_barrier preceded
//    by s_waitcnt lgkmcnt(0) (NOT __syncthreads: avoids vmcnt(0) drain so
//    the next x-chunk's global loads stay in flight across the scan).
//  - x chunk prefetch: 4x float4/thread issued at chunk top, consumed next
//    chunk (~7us later) -> HBM latency fully hidden.

typedef _Float16 f16;
typedef _Float16 f16x2 __attribute__((ext_vector_type(2)));
typedef _Float16 f16x4 __attribute__((ext_vector_type(4)));
typedef _Float16 f16x8 __attribute__((ext_vector_type(8)));
typedef float    f32x4 __attribute__((ext_vector_type(4)));

#define Bv 256
#define Tv 2048
#define Hv 256
#define TC 32
#define NCHUNK (Tv/TC)
#define XS_LD 264   // f16 row stride (pad: 528B -> 2-way banks on A-frag reads)
#define XW_LD 260   // f32 row stride (pad: 1040B -> conflict-free C writes)

#define LGKM_BARRIER() do { \
    asm volatile("s_waitcnt lgkmcnt(0)" ::: "memory"); \
    __builtin_amdgcn_s_barrier(); \
} while (0)

__device__ __forceinline__ float dot2f(f16x2 a, f16x2 b, float c) {
#if __has_builtin(__builtin_amdgcn_fdot2)
    return __builtin_amdgcn_fdot2(a, b, c, false);
#else
    return fmaf((float)a[0], (float)b[0], fmaf((float)a[1], (float)b[1], c));
#endif
}

#define PAIR(v, i) (__builtin_shufflevector((v), (v), 2*(i), 2*(i)+1))

__device__ __forceinline__ f16x4 cvt4(float4 v) {
    f16x4 r; r[0] = (f16)v.x; r[1] = (f16)v.y; r[2] = (f16)v.z; r[3] = (f16)v.w;
    return r;
}

__global__ __launch_bounds__(512, 2)
void HiddenLayer_704374636647_kernel(const float* __restrict__ x,
                                     const float* __restrict__ wx,
                                     const float* __restrict__ wh,
                                     const float* __restrict__ bias,
                                     float* __restrict__ out)
{
    __shared__ __align__(16) f16   xs16[2][TC][XS_LD];  // ~33.8 KB
    __shared__ __align__(16) float xwc[TC][XW_LD];      // ~33.3 KB
    __shared__ __align__(16) f16   hbuf[2][Hv];         //   1 KB

    const int tid   = threadIdx.x;
    const int wave  = tid >> 6;
    const int lane  = tid & 63;
    const int b     = blockIdx.x;
    const int wbase = wave * 32;            // wave's 32-col slice
    const int jcol  = wbase + (lane & 31);  // this lane's output column
    const int q     = lane >> 5;            // k-half (0/1) for recurrence

    const float* xb = x + (size_t)b * Tv * Hv;

    // ---- issue chunk-0 x loads first (overlap weight-loading latency)
    const int rowoff = (tid >> 6) * Hv + (tid & 63) * 4;   // s-th load at +s*8 rows
    float4 xr0, xr1, xr2, xr3;
#define LOADX(cc) do { const float* p_ = xb + (size_t)(cc) * (TC * Hv) + rowoff; \
    xr0 = *(const float4*)(p_);          xr1 = *(const float4*)(p_ + 8*Hv); \
    xr2 = *(const float4*)(p_ + 16*Hv);  xr3 = *(const float4*)(p_ + 24*Hv); } while (0)
    LOADX(0);

    // ---- wx B-frags (MFMA 16x16x32 f16): bfrag[ni][kt], lane holds col
    //      wbase+ni*16+(lane&15), k = kt*32 + (lane>>4)*8 + 0..7
    f16x8 bfrag[2][8];
    {
        const int  kb = (lane >> 4) * 8;
        const int  n0 = wbase + (lane & 15);
        #pragma unroll
        for (int ni = 0; ni < 2; ++ni) {
            #pragma unroll
            for (int kt = 0; kt < 8; ++kt) {
                const float* p = wx + (size_t)(kt * 32 + kb) * Hv + n0 + ni * 16;
                f16x8 v;
                #pragma unroll
                for (int e = 0; e < 8; ++e) v[e] = (f16)p[(size_t)e * Hv];
                bfrag[ni][kt] = v;
            }
        }
    }

    // ---- wh slice: whr[m] = (wh[q*128+2m][jcol], wh[q*128+2m+1][jcol])
    f16x2 whr[64];
    {
        const float* p = wh + (size_t)(q * 128) * Hv + jcol;
        #pragma unroll 8
        for (int m = 0; m < 64; ++m) {
            f16x2 v; v[0] = (f16)p[(size_t)(2*m) * Hv]; v[1] = (f16)p[(size_t)(2*m+1) * Hv];
            whr[m] = v;
        }
    }

    const float biasc0 = bias[wbase + (lane & 15)];
    const float biasc1 = bias[wbase + 16 + (lane & 15)];

    if (tid < Hv) hbuf[0][tid] = (f16)0.0f;   // h_0 = 0 (covered by barrier below)

    int   cur     = 0;
    float th_keep = 0.0f;
    const int r0 = tid >> 6;          // staging row (s=0)
    const int c4 = (tid & 63) * 4;    // staging col

    for (int c = 0; c < NCHUNK; ++c) {
        const int buf = c & 1;

        // ---- stage prefetched x (f32->f16) into xs16[buf]
        *(f16x4*)&xs16[buf][r0     ][c4] = cvt4(xr0);
        *(f16x4*)&xs16[buf][r0 +  8][c4] = cvt4(xr1);
        *(f16x4*)&xs16[buf][r0 + 16][c4] = cvt4(xr2);
        *(f16x4*)&xs16[buf][r0 + 24][c4] = cvt4(xr3);

        // ---- issue prefetch for next chunk (stays in flight across the scan)
        const int cn = (c + 1 < NCHUNK) ? c + 1 : c;
        LOADX(cn);

        LGKM_BARRIER();   // xs16 visible (and hbuf[0] zeros at c==0)

        // ---- chunk GEMM: xwc = xs16 @ wx + bias  (M=32, N=256/wave:32, K=256)
        {
            f32x4 acc00 = {0,0,0,0}, acc01 = {0,0,0,0}, acc10 = {0,0,0,0}, acc11 = {0,0,0,0};
            const int arow  = lane & 15;
            const int akoff = (lane >> 4) * 8;
            #pragma unroll
            for (int kt = 0; kt < 8; ++kt) {
                f16x8 a0 = *(const f16x8*)&xs16[buf][arow     ][kt * 32 + akoff];
                f16x8 a1 = *(const f16x8*)&xs16[buf][arow + 16][kt * 32 + akoff];
                acc00 = __builtin_amdgcn_mfma_f32_16x16x32_f16(a0, bfrag[0][kt], acc00, 0, 0, 0);
                acc10 = __builtin_amdgcn_mfma_f32_16x16x32_f16(a1, bfrag[0][kt], acc10, 0, 0, 0);
                acc01 = __builtin_amdgcn_mfma_f32_16x16x32_f16(a0, bfrag[1][kt], acc01, 0, 0, 0);
                acc11 = __builtin_amdgcn_mfma_f32_16x16x32_f16(a1, bfrag[1][kt], acc11, 0, 0, 0);
            }
            // C/D layout: col = lane&15, row = (lane>>4)*4 + r   (m89-verified)
            const int crow = (lane >> 4) * 4;
            const int ccol = wbase + (lane & 15);
            #pragma unroll
            for (int r = 0; r < 4; ++r) {
                xwc[crow + r     ][ccol     ] = acc00[r] + biasc0;
                xwc[crow + r + 16][ccol     ] = acc10[r] + biasc0;
                xwc[crow + r     ][ccol + 16] = acc01[r] + biasc1;
                xwc[crow + r + 16][ccol + 16] = acc11[r] + biasc1;
            }
        }

        LGKM_BARRIER();   // xwc visible

        // ---- scan TC steps, 1 barrier each (double-buffered h)
        #pragma unroll 2
        for (int ts = 0; ts < TC; ++ts) {
            const f16* hp = &hbuf[cur][q * 128];
            float a0 = 0.f, a1 = 0.f, a2 = 0.f, a3 = 0.f;
            #pragma unroll
            for (int g = 0; g < 4; ++g) {
                f16x8 hA = *(const f16x8*)(hp + g * 32 +  0);
                f16x8 hB = *(const f16x8*)(hp + g * 32 +  8);
                f16x8 hC = *(const f16x8*)(hp + g * 32 + 16);
                f16x8 hD = *(const f16x8*)(hp + g * 32 + 24);
                const int m0 = g * 16;
                a0 = dot2f(PAIR(hA, 0), whr[m0 +  0], a0);
                a1 = dot2f(PAIR(hA, 1), whr[m0 +  1], a1);
                a2 = dot2f(PAIR(hA, 2), whr[m0 +  2], a2);
                a3 = dot2f(PAIR(hA, 3), whr[m0 +  3], a3);
                a0 = dot2f(PAIR(hB, 0), whr[m0 +  4], a0);
                a1 = dot2f(PAIR(hB, 1), whr[m0 +  5], a1);
                a2 = dot2f(PAIR(hB, 2), whr[m0 +  6], a2);
                a3 = dot2f(PAIR(hB, 3), whr[m0 +  7], a3);
                a0 = dot2f(PAIR(hC, 0), whr[m0 +  8], a0);
                a1 = dot2f(PAIR(hC, 1), whr[m0 +  9], a1);
                a2 = dot2f(PAIR(hC, 2), whr[m0 + 10], a2);
                a3 = dot2f(PAIR(hC, 3), whr[m0 + 11], a3);
                a0 = dot2f(PAIR(hD, 0), whr[m0 + 12], a0);
                a1 = dot2f(PAIR(hD, 1), whr[m0 + 13], a1);
                a2 = dot2f(PAIR(hD, 2), whr[m0 + 14], a2);
                a3 = dot2f(PAIR(hD, 3), whr[m0 + 15], a3);
            }
            float d = (a0 + a1) + (a2 + a3);
            d += __shfl_xor(d, 32);                 // combine the two k-halves
            float sum = d + xwc[ts][jcol];
            // fast tanh: (e^{2x}-1)/(e^{2x}+1), clamped (tanh(12) rounds to 1.0f)
            float sc = fminf(fmaxf(sum, -12.f), 12.f);
            float e  = __expf(2.f * sc);
            float th = __fdividef(e - 1.f, e + 1.f);
            th_keep = th;
            if (lane < 32) hbuf[cur ^ 1][jcol] = (f16)th;
            LGKM_BARRIER();
            cur ^= 1;
        }
    }

    if (lane < 32) out[(size_t)b * Hv + jcol] = th_keep;
}

extern "C" void kernel_launch(void* const* d_in, const int* in_sizes, int n_in,
                              void* d_out, int out_size, void* d_ws, size_t ws_size,
                              hipStream_t stream) {
    const float* x    = (const float*)d_in[0];   // [B,T,H]
    const float* wx   = (const float*)d_in[1];   // [H,H]
    const float* wh   = (const float*)d_in[2];   // [H,H]
    const float* bias = (const float*)d_in[3];   // [1,H]
    float* out = (float*)d_out;                  // [B,1,H]

    hipLaunchKernelGGL(HiddenLayer_704374636647_kernel,
                       dim3(Bv), dim3(512), 0, stream,
                       x, wx, wh, bias, out);
}

// Round 3
// 1011.598 us; speedup vs baseline: 2.7051x; 1.1618x over previous
//
#include <hip/hip_runtime.h>
#include <math.h>

// Vanilla RNN: h_t = tanh(h_{t-1} @ wh + x_t @ wx + b), out = h_T  [B,1,H]
// B=256, T=2048, H=256, fp32 in/out.
//
// Round 2 design:
//  - 256 blocks (1 batch row/CU) x 512 threads (8 waves). No grid sync.
//  - Projection xw = x@wx+b : f16 MFMA 16x16x32, f32 accum (unchanged).
//  - Recurrence via MFMA "replicated-row" trick: A-frags carry h broadcast
//    into ALL 16 M-rows (each lane reads the same k-slice for its lane>>4
//    group). Then every D row is identical, so each lane holds the full
//    result for col (lane&15) in acc[0] -- no reduction, no shuffles.
//    C is seeded with xw[ts][col] (splat), so the epilogue add is free.
//    wh lives in registers as B-frags (16 x f16x8 = 64 VGPR), same layout
//    as the round-1 GEMM's wx frags (empirically validated).
//  - Per step per wave: 8 broadcast ds_read_b128 (conflict-free) + 16
//    chained MFMA (2 chains x 8) + tanh + 1 ds_write_b16. DS-pipe load
//    ~halves vs round 1; VALU drops ~5x.
//  - h double-buffered -> ONE raw s_barrier/step (lgkmcnt(0) only, no
//    vmcnt drain -> x prefetch stays in flight across the scan).

typedef _Float16 f16;
typedef _Float16 f16x4 __attribute__((ext_vector_type(4)));
typedef _Float16 f16x8 __attribute__((ext_vector_type(8)));
typedef float    f32x4 __attribute__((ext_vector_type(4)));

#define Bv 256
#define Tv 2048
#define Hv 256
#define TC 32
#define NCHUNK (Tv/TC)
#define XS_LD 264   // f16 row stride (pad: 528B -> 2-way banks on A-frag reads)
#define XW_LD 260   // f32 row stride

#define LGKM_BARRIER() do { \
    asm volatile("s_waitcnt lgkmcnt(0)" ::: "memory"); \
    __builtin_amdgcn_s_barrier(); \
} while (0)

__device__ __forceinline__ f16x4 cvt4(float4 v) {
    f16x4 r; r[0] = (f16)v.x; r[1] = (f16)v.y; r[2] = (f16)v.z; r[3] = (f16)v.w;
    return r;
}

__global__ __launch_bounds__(512, 2)
void HiddenLayer_704374636647_kernel(const float* __restrict__ x,
                                     const float* __restrict__ wx,
                                     const float* __restrict__ wh,
                                     const float* __restrict__ bias,
                                     float* __restrict__ out)
{
    __shared__ __align__(16) f16   xs16[2][TC][XS_LD];  // ~33.8 KB
    __shared__ __align__(16) float xwc[TC][XW_LD];      // ~33.3 KB
    __shared__ __align__(16) f16   hbuf[2][Hv];         //   1 KB

    const int tid   = threadIdx.x;
    const int wave  = tid >> 6;
    const int lane  = tid & 63;
    const int b     = blockIdx.x;
    const int wbase = wave * 32;            // wave's 32-col slice

    const float* xb = x + (size_t)b * Tv * Hv;

    // ---- issue chunk-0 x loads first (overlap weight-loading latency)
    const int rowoff = (tid >> 6) * Hv + (tid & 63) * 4;
    float4 xr0, xr1, xr2, xr3;
#define LOADX(cc) do { const float* p_ = xb + (size_t)(cc) * (TC * Hv) + rowoff; \
    xr0 = *(const float4*)(p_);          xr1 = *(const float4*)(p_ + 8*Hv); \
    xr2 = *(const float4*)(p_ + 16*Hv);  xr3 = *(const float4*)(p_ + 24*Hv); } while (0)
    LOADX(0);

    // ---- B-frags (MFMA 16x16x32 f16): lane holds col wbase+ni*16+(lane&15),
    //      k = kt*32 + (lane>>4)*8 + e.  bfrag <- wx, whf <- wh.
    f16x8 bfrag[2][8], whf[2][8];
    {
        const int kb = (lane >> 4) * 8;
        const int n0 = wbase + (lane & 15);
        #pragma unroll
        for (int ni = 0; ni < 2; ++ni) {
            #pragma unroll
            for (int kt = 0; kt < 8; ++kt) {
                const float* pw = wx + (size_t)(kt * 32 + kb) * Hv + n0 + ni * 16;
                const float* ph = wh + (size_t)(kt * 32 + kb) * Hv + n0 + ni * 16;
                f16x8 vw, vh;
                #pragma unroll
                for (int e = 0; e < 8; ++e) {
                    vw[e] = (f16)pw[(size_t)e * Hv];
                    vh[e] = (f16)ph[(size_t)e * Hv];
                }
                bfrag[ni][kt] = vw;
                whf[ni][kt]   = vh;
            }
        }
    }

    const float biasc0 = bias[wbase + (lane & 15)];
    const float biasc1 = bias[wbase + 16 + (lane & 15)];

    if (tid < Hv) hbuf[0][tid] = (f16)0.0f;   // h_0 = 0

    int   cur     = 0;
    float th_keep = 0.0f;
    const int r0 = tid >> 6;
    const int c4 = (tid & 63) * 4;
    const int g16 = ((lane >> 4) & 3) * 8;    // A-frag k-offset within a kt

    for (int c = 0; c < NCHUNK; ++c) {
        const int buf = c & 1;

        // ---- stage prefetched x (f32->f16)
        *(f16x4*)&xs16[buf][r0     ][c4] = cvt4(xr0);
        *(f16x4*)&xs16[buf][r0 +  8][c4] = cvt4(xr1);
        *(f16x4*)&xs16[buf][r0 + 16][c4] = cvt4(xr2);
        *(f16x4*)&xs16[buf][r0 + 24][c4] = cvt4(xr3);

        const int cn = (c + 1 < NCHUNK) ? c + 1 : c;
        LOADX(cn);

        LGKM_BARRIER();   // xs16 visible (and hbuf[0] zeros at c==0)

        // ---- chunk GEMM: xwc = xs16 @ wx + bias
        {
            f32x4 acc00 = {0,0,0,0}, acc01 = {0,0,0,0}, acc10 = {0,0,0,0}, acc11 = {0,0,0,0};
            const int arow  = lane & 15;
            const int akoff = (lane >> 4) * 8;
            #pragma unroll
            for (int kt = 0; kt < 8; ++kt) {
                f16x8 a0 = *(const f16x8*)&xs16[buf][arow     ][kt * 32 + akoff];
                f16x8 a1 = *(const f16x8*)&xs16[buf][arow + 16][kt * 32 + akoff];
                acc00 = __builtin_amdgcn_mfma_f32_16x16x32_f16(a0, bfrag[0][kt], acc00, 0, 0, 0);
                acc10 = __builtin_amdgcn_mfma_f32_16x16x32_f16(a1, bfrag[0][kt], acc10, 0, 0, 0);
                acc01 = __builtin_amdgcn_mfma_f32_16x16x32_f16(a0, bfrag[1][kt], acc01, 0, 0, 0);
                acc11 = __builtin_amdgcn_mfma_f32_16x16x32_f16(a1, bfrag[1][kt], acc11, 0, 0, 0);
            }
            const int crow = (lane >> 4) * 4;
            const int ccol = wbase + (lane & 15);
            #pragma unroll
            for (int r = 0; r < 4; ++r) {
                xwc[crow + r     ][ccol     ] = acc00[r] + biasc0;
                xwc[crow + r + 16][ccol     ] = acc10[r] + biasc0;
                xwc[crow + r     ][ccol + 16] = acc01[r] + biasc1;
                xwc[crow + r + 16][ccol + 16] = acc11[r] + biasc1;
            }
        }

        LGKM_BARRIER();   // xwc visible

        // ---- scan TC steps, 1 barrier each (double-buffered h)
        #pragma unroll 2
        for (int ts = 0; ts < TC; ++ts) {
            // seed C with xw (bias already folded in)
            const float xw0 = xwc[ts][wbase + (lane & 15)];
            const float xw1 = xwc[ts][wbase + 16 + (lane & 15)];
            f32x4 acc0 = {xw0, xw0, xw0, xw0};
            f32x4 acc1 = {xw1, xw1, xw1, xw1};

            const f16* hp = hbuf[cur];
            #pragma unroll
            for (int kt = 0; kt < 8; ++kt) {
                // replicated-row A-frag: every lane reads its k-slice of h;
                // 4 distinct 16B lines per read -> conflict-free broadcast
                f16x8 ha = *(const f16x8*)(hp + kt * 32 + g16);
                acc0 = __builtin_amdgcn_mfma_f32_16x16x32_f16(ha, whf[0][kt], acc0, 0, 0, 0);
                acc1 = __builtin_amdgcn_mfma_f32_16x16x32_f16(ha, whf[1][kt], acc1, 0, 0, 0);
            }

            // all D rows identical -> acc[0] holds the full sum for this
            // lane's column: lanes 0-15 cols wbase+0..15 (acc0), 16-31 +16 (acc1)
            const float s  = (lane & 16) ? acc1[0] : acc0[0];
            const float sc = fminf(fmaxf(s, -12.f), 12.f);
            const float e  = __expf(2.f * sc);
            const float th = __fdividef(e - 1.f, e + 1.f);
            th_keep = th;
            if (lane < 32) hbuf[cur ^ 1][wbase + lane] = (f16)th;
            LGKM_BARRIER();
            cur ^= 1;
        }
    }

    if (lane < 32) out[(size_t)b * Hv + wbase + lane] = th_keep;
}

extern "C" void kernel_launch(void* const* d_in, const int* in_sizes, int n_in,
                              void* d_out, int out_size, void* d_ws, size_t ws_size,
                              hipStream_t stream) {
    const float* x    = (const float*)d_in[0];   // [B,T,H]
    const float* wx   = (const float*)d_in[1];   // [H,H]
    const float* wh   = (const float*)d_in[2];   // [H,H]
    const float* bias = (const float*)d_in[3];   // [1,H]
    float* out = (float*)d_out;                  // [B,1,H]

    hipLaunchKernelGGL(HiddenLayer_704374636647_kernel,
                       dim3(Bv), dim3(512), 0, stream,
                       x, wx, wh, bias, out);
}

// Round 4
// 1004.220 us; speedup vs baseline: 2.7249x; 1.0073x over previous
//
#include <hip/hip_runtime.h>
#include <math.h>

// Vanilla RNN: h_t = tanh(h_{t-1} @ wh + x_t @ wx + b), out = h_T  [B,1,H]
// B=256, T=2048, H=256, fp32 in/out.
//
// Round 3: wave specialization. 256 blocks (1 batch row/CU) x 512 threads.
//  - Waves 0-3 (SCAN): recurrence via MFMA replicated-row trick, 64 cols/wave
//    (4 col-tiles). wh frags in regs (whf[4][8] = 128 VGPR). Per step:
//    1 b128 xwc-seed read + 8 broadcast b128 h reads + 32 MFMA + tanh +
//    1 b16 h write -> 40 DS inst/CU/step (vs 88 in round 2).
//  - Waves 4-7 (GEMM): produce chunk c+1's xw = x@wx + b DURING chunk c's
//    scan, paced on the same 32 per-step barriers (2 stage + 8 kt-slices +
//    1 write + 1 prefetch + 20 empty = 32 barriers, matching the scan's 32).
//    wx frags in regs (128 VGPR). GEMM+staging fully hidden under the scan.
//  - xwc4[parity][cq][ts][4] layout: scan lane reads its 4 cols for step ts
//    as ONE ds_read_b128; GEMM waves write it via 4-acc transposes (b128).
//    ts-dim padded to 33 -> 2-way banks on the cq-strided read (free).
//  - ONE raw s_barrier/step (lgkmcnt(0) only; vmcnt NOT drained so the
//    GEMM waves' global x prefetch stays in flight across the whole scan).

typedef _Float16 f16;
typedef _Float16 f16x4 __attribute__((ext_vector_type(4)));
typedef _Float16 f16x8 __attribute__((ext_vector_type(8)));
typedef float    f32x4 __attribute__((ext_vector_type(4)));

#define Bv 256
#define Tv 2048
#define Hv 256
#define TC 32
#define NCHUNK (Tv/TC)
#define XS_LD 264          // f16 row stride (528B -> 2-way banks, free)
#define XW_TS (TC+1)       // ts-dim pad: cq stride 33*16B=528B -> 2-way banks

#define LGKM_BARRIER() do { \
    asm volatile("s_waitcnt lgkmcnt(0)" ::: "memory"); \
    __builtin_amdgcn_s_barrier(); \
} while (0)

#define MFMA16(a, b, c) __builtin_amdgcn_mfma_f32_16x16x32_f16((a), (b), (c), 0, 0, 0)

__device__ __forceinline__ f16x4 cvt4(float4 v) {
    f16x4 r; r[0] = (f16)v.x; r[1] = (f16)v.y; r[2] = (f16)v.z; r[3] = (f16)v.w;
    return r;
}

__global__ __launch_bounds__(512, 1)
void HiddenLayer_704374636647_kernel(const float* __restrict__ x,
                                     const float* __restrict__ wx,
                                     const float* __restrict__ wh,
                                     const float* __restrict__ bias,
                                     float* __restrict__ out)
{
    __shared__ __align__(16) f16   xs16[TC][XS_LD];        // 16.9 KB
    __shared__ __align__(16) float xwc4[2][64][XW_TS][4];  // 67.6 KB
    __shared__ __align__(16) f16   hbuf[2][Hv];            //  1.0 KB

    const int  tid   = threadIdx.x;
    const int  wave  = tid >> 6;
    const int  lane  = tid & 63;
    const int  b     = blockIdx.x;
    const bool sw    = (wave < 4);            // scan role
    const int  sg    = sw ? wave : wave - 4;  // role-group 0..3
    const int  wbase = sg * 64;               // 64-col slice owned by group
    const int  l15   = lane & 15;
    const int  grp   = lane >> 4;             // 0..3
    const int  cq    = sg * 16 + l15;         // xwc4 column-quad index
    const int  koff  = grp * 8;               // A-frag k-offset

    const float* xb = x + (size_t)b * Tv * Hv;

    // ---- GEMM waves: global x prefetch registers (8 rows x 4 f32/lane)
    float4 xr0, xr1, xr2, xr3, xr4, xr5, xr6, xr7;
#define LOADX(cc) do { const float* p_ = xb + ((size_t)(cc) * TC + sg * 8) * Hv + lane * 4; \
    xr0 = *(const float4*)(p_);          xr1 = *(const float4*)(p_ +     Hv); \
    xr2 = *(const float4*)(p_ + 2 * Hv); xr3 = *(const float4*)(p_ + 3 * Hv); \
    xr4 = *(const float4*)(p_ + 4 * Hv); xr5 = *(const float4*)(p_ + 5 * Hv); \
    xr6 = *(const float4*)(p_ + 6 * Hv); xr7 = *(const float4*)(p_ + 7 * Hv); } while (0)

    if (!sw) LOADX(0);

    // ---- weight B-frags (identical layout for both roles, different matrix):
    //      tile t covers cols wbase + t*16 + l15; k = kt*32 + grp*8 + e
    const float* wsrc = sw ? wh : wx;
    f16x8 wf[4][8];
    #pragma unroll
    for (int t = 0; t < 4; ++t) {
        #pragma unroll
        for (int kt = 0; kt < 8; ++kt) {
            const float* p = wsrc + (size_t)(kt * 32 + koff) * Hv + wbase + t * 16 + l15;
            f16x8 v;
            #pragma unroll
            for (int e = 0; e < 8; ++e) v[e] = (f16)p[(size_t)e * Hv];
            wf[t][kt] = v;
        }
    }

    float bc0 = 0.f, bc1 = 0.f, bc2 = 0.f, bc3 = 0.f;
    if (!sw) {
        bc0 = bias[wbase + l15];      bc1 = bias[wbase + 16 + l15];
        bc2 = bias[wbase + 32 + l15]; bc3 = bias[wbase + 48 + l15];
    }

    if (sw) hbuf[0][tid] = (f16)0.0f;   // h_0 = 0 (tid 0..255 == scan lanes)

    int   cur     = 0;
    float th_keep = 0.0f;

    #pragma unroll 1
    for (int phase = 0; phase <= NCHUNK; ++phase) {
        if (sw) {
            // ================= SCAN ROLE =================
            if (phase == 0) {
                for (int i = 0; i < TC; ++i) LGKM_BARRIER();
            } else {
                const int ps = (phase - 1) & 1;
                for (int ts = 0; ts < TC; ++ts) {
                    const f32x4 xw = *(const f32x4*)&xwc4[ps][cq][ts][0];
                    const f16*  hp = &hbuf[cur][koff];
                    f32x4 a0 = {xw[0], 0.f, 0.f, 0.f};
                    f32x4 a1 = {xw[1], 0.f, 0.f, 0.f};
                    f32x4 a2 = {xw[2], 0.f, 0.f, 0.f};
                    f32x4 a3 = {xw[3], 0.f, 0.f, 0.f};
                    #pragma unroll
                    for (int kt = 0; kt < 8; ++kt) {
                        // replicated-row A-frag: 4 distinct 16B lines/wave -> broadcast
                        f16x8 ha = *(const f16x8*)(hp + kt * 32);
                        a0 = MFMA16(ha, wf[0][kt], a0);
                        a1 = MFMA16(ha, wf[1][kt], a1);
                        a2 = MFMA16(ha, wf[2][kt], a2);
                        a3 = MFMA16(ha, wf[3][kt], a3);
                    }
                    // D rows identical -> reg0 holds full sum for col of tile t;
                    // this lane owns tile (grp): col = wbase + grp*16 + l15 = wbase+lane
                    float s01 = (grp & 1) ? a1[0] : a0[0];
                    float s23 = (grp & 1) ? a3[0] : a2[0];
                    float s   = (grp & 2) ? s23 : s01;
                    float scv = fminf(fmaxf(s, -12.f), 12.f);
                    float e   = __expf(2.f * scv);
                    float th  = __fdividef(e - 1.f, e + 1.f);
                    th_keep = th;
                    hbuf[cur ^ 1][wbase + lane] = (f16)th;
                    LGKM_BARRIER();
                    cur ^= 1;
                }
            }
        } else {
            // ================= GEMM ROLE (produces chunk `phase`) =================
            if (phase < NCHUNK) {
                {   // slice 0: stage rows sg*8+0..3 (f32->f16)
                    f16* r = &xs16[sg * 8][lane * 4];
                    *(f16x4*)(r)            = cvt4(xr0);
                    *(f16x4*)(r + XS_LD)    = cvt4(xr1);
                    *(f16x4*)(r + 2*XS_LD)  = cvt4(xr2);
                    *(f16x4*)(r + 3*XS_LD)  = cvt4(xr3);
                }
                LGKM_BARRIER();
                {   // slice 1: stage rows sg*8+4..7
                    f16* r = &xs16[sg * 8 + 4][lane * 4];
                    *(f16x4*)(r)            = cvt4(xr4);
                    *(f16x4*)(r + XS_LD)    = cvt4(xr5);
                    *(f16x4*)(r + 2*XS_LD)  = cvt4(xr6);
                    *(f16x4*)(r + 3*XS_LD)  = cvt4(xr7);
                }
                LGKM_BARRIER();
                // slices 2-9: one kt each. A-rows = timesteps; bias seeded in C.
                f32x4 A0 = {bc0,bc0,bc0,bc0}, A1 = {bc1,bc1,bc1,bc1};
                f32x4 A2 = {bc2,bc2,bc2,bc2}, A3 = {bc3,bc3,bc3,bc3};
                f32x4 B0 = A0, B1 = A1, B2 = A2, B3 = A3;
                #pragma unroll
                for (int kt = 0; kt < 8; ++kt) {
                    f16x8 u0 = *(const f16x8*)&xs16[l15     ][kt * 32 + koff];
                    f16x8 u1 = *(const f16x8*)&xs16[l15 + 16][kt * 32 + koff];
                    A0 = MFMA16(u0, wf[0][kt], A0);
                    A1 = MFMA16(u0, wf[1][kt], A1);
                    A2 = MFMA16(u0, wf[2][kt], A2);
                    A3 = MFMA16(u0, wf[3][kt], A3);
                    B0 = MFMA16(u1, wf[0][kt], B0);
                    B1 = MFMA16(u1, wf[1][kt], B1);
                    B2 = MFMA16(u1, wf[2][kt], B2);
                    B3 = MFMA16(u1, wf[3][kt], B3);
                    LGKM_BARRIER();
                }
                // slice 10: transpose accs -> xwc4 (row = timestep, 4 cols/line)
                {
                    const int pw = phase & 1;
                    #pragma unroll
                    for (int r = 0; r < 4; ++r) {
                        f32x4 v = {A0[r], A1[r], A2[r], A3[r]};
                        *(f32x4*)&xwc4[pw][cq][grp * 4 + r][0] = v;
                        f32x4 w = {B0[r], B1[r], B2[r], B3[r]};
                        *(f32x4*)&xwc4[pw][cq][16 + grp * 4 + r][0] = w;
                    }
                }
                LGKM_BARRIER();
                // slice 11: issue next chunk's global prefetch (in flight across scan)
                if (phase + 1 < NCHUNK) LOADX(phase + 1);
                LGKM_BARRIER();
                // slices 12-31: pace the scan
                for (int i = 12; i < TC; ++i) LGKM_BARRIER();
            } else {
                for (int i = 0; i < TC; ++i) LGKM_BARRIER();
            }
        }
    }

    // th_keep's col = wbase + grp*16 + l15 = wbase + lane -> coalesced store
    if (sw) out[(size_t)b * Hv + wbase + lane] = th_keep;
}

extern "C" void kernel_launch(void* const* d_in, const int* in_sizes, int n_in,
                              void* d_out, int out_size, void* d_ws, size_t ws_size,
                              hipStream_t stream) {
    const float* x    = (const float*)d_in[0];   // [B,T,H]
    const float* wx   = (const float*)d_in[1];   // [H,H]
    const float* wh   = (const float*)d_in[2];   // [H,H]
    const float* bias = (const float*)d_in[3];   // [1,H]
    float* out = (float*)d_out;                  // [B,1,H]

    hipLaunchKernelGGL(HiddenLayer_704374636647_kernel,
                       dim3(Bv), dim3(512), 0, stream,
                       x, wx, wh, bias, out);
}